// Round 2
// baseline (359.416 us; speedup 1.0000x reference)
//
#include <hip/hip_runtime.h>

// Fused single-head causal attention, B=512, T=256, C=384, HS=64.
// prep kernel packs Wq|Wk|Wv into bf16 W^T [192][384] in d_ws.
// Main kernel: 1 block per batch, 512 threads (8 waves).
//   Phase 1: QKV = x @ W via mfma_16x16x32_bf16; Q(*scale*log2e)/K -> LDS
//            [256][64] bf16, V -> LDS transposed [64][256]; all XOR-swizzled.
//   Phase 2: per-wave flash attention over Q-tile pair {w, 15-w} (balanced:
//            always 9 K-tile-steps total), online softmax in exp2 domain,
//            P via per-wave padded LDS buffer, PV mfma, fp32 accum, /l epilogue.

typedef float f32x4 __attribute__((ext_vector_type(4)));
typedef __bf16 bf16x8 __attribute__((ext_vector_type(8)));

constexpr int T_ = 256;
constexpr int C_ = 384;
constexpr int HS_ = 64;

__device__ __forceinline__ short f2bs(float v) {
  __bf16 b = (__bf16)v;
  return __builtin_bit_cast(short, b);
}

__device__ __forceinline__ f32x4 mfma16(bf16x8 a, bf16x8 b, f32x4 c) {
  return __builtin_amdgcn_mfma_f32_16x16x32_bf16(a, b, c, 0, 0, 0);
}

// W^T pack: wt[n][k] = W_{n/64}[k][n%64] as bf16, n in [0,192), k in [0,384)
__global__ void prep_wt_kernel(const float* __restrict__ Wq,
                               const float* __restrict__ Wk,
                               const float* __restrict__ Wv,
                               short* __restrict__ wt) {
  int idx = blockIdx.x * 256 + threadIdx.x;
  if (idx >= 192 * 384) return;
  int n = idx / 384;
  int k = idx - n * 384;
  const float* W = (n < 64) ? Wq : (n < 128) ? Wk : Wv;
  int h = n & 63;
  wt[idx] = f2bs(W[k * 64 + h]);
}

// Swizzled LDS indices (element units; flips bits 3..5 of the fast dim so the
// 16-row stride-128B reads spread across all 8 16B slots per 8-row stripe).
__device__ __forceinline__ int qswz(int row, int h) {
  return row * 64 + (h ^ ((row & 7) << 3));
}
__device__ __forceinline__ int vswz(int h, int tok) {
  return h * 256 + (tok ^ ((h & 7) << 3));
}

__global__ __launch_bounds__(512, 1) void fused_head(const float* __restrict__ x,
                                                     const short* __restrict__ wt,
                                                     float* __restrict__ out) {
  __shared__ __align__(16) short QS[256 * 64];   // 32 KB, Q*scale*log2e, swizzled
  __shared__ __align__(16) short KS[256 * 64];   // 32 KB, swizzled
  __shared__ __align__(16) short VT[64 * 256];   // 32 KB, V^T, swizzled
  __shared__ __align__(16) short PB[8][16 * 40]; // 10 KB, per-wave P, pad 40 (5x16B)

  const int b = blockIdx.x;
  const int tid = threadIdx.x;
  const int w = tid >> 6;         // wave id 0..7
  const int lr = tid & 15;        // lane % 16: frag row (A) / col (B, C)
  const int lg = (tid & 63) >> 4; // lane group 0..3

  const float* xb = x + (size_t)b * (T_ * C_);

  // ---------------- Phase 1: QKV projection ----------------
  // Wave w computes output rows [32w, 32w+32): M-tiles {2w, 2w+1}, all 12 N-tiles.
  f32x4 acc[2][12];
#pragma unroll
  for (int m = 0; m < 2; ++m)
#pragma unroll
    for (int nt = 0; nt < 12; ++nt) acc[m][nt] = f32x4{0.f, 0.f, 0.f, 0.f};

#pragma unroll
  for (int ks = 0; ks < 12; ++ks) {
    bf16x8 a[2];
#pragma unroll
    for (int m = 0; m < 2; ++m) {
      int row = (2 * w + m) * 16 + lr;
      const f32x4* p = reinterpret_cast<const f32x4*>(xb + row * C_ + ks * 32 + lg * 8);
      f32x4 f0 = p[0];
      f32x4 f1 = p[1];
      bf16x8 t;
      t[0] = (__bf16)f0[0]; t[1] = (__bf16)f0[1]; t[2] = (__bf16)f0[2]; t[3] = (__bf16)f0[3];
      t[4] = (__bf16)f1[0]; t[5] = (__bf16)f1[1]; t[6] = (__bf16)f1[2]; t[7] = (__bf16)f1[3];
      a[m] = t;
    }
#pragma unroll
    for (int nt = 0; nt < 12; ++nt) {
      bf16x8 bw = *reinterpret_cast<const bf16x8*>(wt + (nt * 16 + lr) * 384 + ks * 32 + lg * 8);
      acc[0][nt] = mfma16(a[0], bw, acc[0][nt]);
      acc[1][nt] = mfma16(a[1], bw, acc[1][nt]);
    }
  }

  // Write Q/K/V^T to LDS (C layout: col = lr, row = lg*4 + j within tile).
  // Q pre-scaled by HS^-0.5 * log2(e) so softmax runs in the exp2 domain.
  const float QSCALE = 0.125f * 1.44269504f;
#pragma unroll
  for (int nt = 0; nt < 12; ++nt) {
    const int which = nt >> 2;
    const int hb = (nt & 3) * 16 + lr;
#pragma unroll
    for (int m = 0; m < 2; ++m) {
      const int rbase = (2 * w + m) * 16 + lg * 4;
#pragma unroll
      for (int j = 0; j < 4; ++j) {
        int row = rbase + j;
        float v = acc[m][nt][j];
        if (which == 0)      QS[qswz(row, hb)] = f2bs(v * QSCALE);
        else if (which == 1) KS[qswz(row, hb)] = f2bs(v);
        else                 VT[vswz(hb, row)] = f2bs(v);
      }
    }
  }

  __syncthreads();

  // ---------------- Phase 2: causal flash attention ----------------
  // Wave w handles Q-tiles t = w and t = 15-w (always 9 K-tile-steps total).
  for (int pass = 0; pass < 2; ++pass) {
    const int t = pass ? (15 - w) : w;
    const int qrow = t * 16 + lr;
    bf16x8 aq0 = *reinterpret_cast<const bf16x8*>(&QS[qswz(qrow, lg * 8)]);
    bf16x8 aq1 = *reinterpret_cast<const bf16x8*>(&QS[qswz(qrow, 32 + lg * 8)]);

    f32x4 o[4];
    float mrun[4], lrun[4];
#pragma unroll
    for (int nt = 0; nt < 4; ++nt) o[nt] = f32x4{0.f, 0.f, 0.f, 0.f};
#pragma unroll
    for (int j = 0; j < 4; ++j) { mrun[j] = -1e30f; lrun[j] = 0.f; }

    const int nkt = (t >> 1) + 1; // K-tiles of 32 needed for causal coverage
    for (int kt = 0; kt < nkt; ++kt) {
      // S2 = (Q*scale*log2e) @ K^T for a 16x32 strip (exp2-domain scores)
      f32x4 s0 = f32x4{0.f, 0.f, 0.f, 0.f};
      f32x4 s1 = f32x4{0.f, 0.f, 0.f, 0.f};
      {
        int kr0 = kt * 32 + lr;
        int kr1 = kr0 + 16;
        bf16x8 b00 = *reinterpret_cast<const bf16x8*>(&KS[qswz(kr0, lg * 8)]);
        bf16x8 b01 = *reinterpret_cast<const bf16x8*>(&KS[qswz(kr0, 32 + lg * 8)]);
        bf16x8 b10 = *reinterpret_cast<const bf16x8*>(&KS[qswz(kr1, lg * 8)]);
        bf16x8 b11 = *reinterpret_cast<const bf16x8*>(&KS[qswz(kr1, 32 + lg * 8)]);
        s0 = mfma16(aq0, b00, s0);
        s0 = mfma16(aq1, b01, s0);
        s1 = mfma16(aq0, b10, s1);
        s1 = mfma16(aq1, b11, s1);
      }

      // Causal mask — only the last K-tile can straddle the diagonal.
      if (kt == nkt - 1) {
#pragma unroll
        for (int j = 0; j < 4; ++j) {
          int row = t * 16 + lg * 4 + j;
          if (kt * 32 + lr > row)      s0[j] = -1e30f;
          if (kt * 32 + 16 + lr > row) s1[j] = -1e30f;
        }
      }

      // Online softmax in exp2 domain (row r: 16 lanes of group r/4, elem j=r%4).
      float alpha[4];
#pragma unroll
      for (int j = 0; j < 4; ++j) {
        float mx = fmaxf(s0[j], s1[j]);
        mx = fmaxf(mx, __shfl_xor(mx, 1));
        mx = fmaxf(mx, __shfl_xor(mx, 2));
        mx = fmaxf(mx, __shfl_xor(mx, 4));
        mx = fmaxf(mx, __shfl_xor(mx, 8));
        float mnew = fmaxf(mrun[j], mx);
        float al = exp2f(mrun[j] - mnew);
        mrun[j] = mnew;
        alpha[j] = al;
        float e0 = exp2f(s0[j] - mnew);
        float e1 = exp2f(s1[j] - mnew);
        float rs = e0 + e1;
        rs += __shfl_xor(rs, 1);
        rs += __shfl_xor(rs, 2);
        rs += __shfl_xor(rs, 4);
        rs += __shfl_xor(rs, 8);
        lrun[j] = lrun[j] * al + rs;
        int prow = lg * 4 + j;
        PB[w][prow * 40 + lr] = f2bs(e0);
        PB[w][prow * 40 + 16 + lr] = f2bs(e1);
      }

      // Rescale O by alpha (per row), then O += P @ V
#pragma unroll
      for (int nt = 0; nt < 4; ++nt) {
        o[nt][0] *= alpha[0];
        o[nt][1] *= alpha[1];
        o[nt][2] *= alpha[2];
        o[nt][3] *= alpha[3];
      }
      bf16x8 ap = *reinterpret_cast<const bf16x8*>(&PB[w][lr * 40 + lg * 8]);
#pragma unroll
      for (int nt = 0; nt < 4; ++nt) {
        int h = nt * 16 + lr;
        bf16x8 bv = *reinterpret_cast<const bf16x8*>(&VT[vswz(h, kt * 32 + lg * 8)]);
        o[nt] = mfma16(ap, bv, o[nt]);
      }
    }

    // Epilogue: O / l, store fp32.
    float inv[4];
#pragma unroll
    for (int j = 0; j < 4; ++j) inv[j] = 1.0f / lrun[j];
    float* ob = out + ((size_t)b * T_ + t * 16 + lg * 4) * HS_;
#pragma unroll
    for (int nt = 0; nt < 4; ++nt)
#pragma unroll
      for (int j = 0; j < 4; ++j)
        ob[j * HS_ + nt * 16 + lr] = o[nt][j] * inv[j];
  }
}

extern "C" void kernel_launch(void* const* d_in, const int* in_sizes, int n_in,
                              void* d_out, int out_size, void* d_ws, size_t ws_size,
                              hipStream_t stream) {
  const float* x = (const float*)d_in[0];
  const float* Wq = (const float*)d_in[1];
  const float* Wk = (const float*)d_in[2];
  const float* Wv = (const float*)d_in[3];
  float* out = (float*)d_out;
  short* wt = (short*)d_ws; // 192*384 bf16 = 147456 B of workspace

  prep_wt_kernel<<<288, 256, 0, stream>>>(Wq, Wk, Wv, wt);
  fused_head<<<512, 512, 0, stream>>>(x, wt, out);
}